// Round 11
// baseline (9071.741 us; speedup 1.0000x reference)
//
#include <hip/hip_runtime.h>

#define Bb 256
#define Tt 512
#define Dd 512
#define Hh 512
#define KTOT 1024
#define FOURH 2048

typedef __attribute__((ext_vector_type(8))) short bf16x8;
typedef __attribute__((ext_vector_type(4))) float f32x4;

__device__ __forceinline__ unsigned short f2bf(float f) {
    union { float f; unsigned u; } x; x.f = f;
    unsigned u = x.u;
    unsigned r = u + 0x7FFFu + ((u >> 16) & 1u);
    return (unsigned short)(r >> 16);
}
__device__ __forceinline__ float bf2f(unsigned short s) {
    union { unsigned u; float f; } x; x.u = ((unsigned)s) << 16;
    return x.f;
}

__device__ __forceinline__ uint4 load16_sc0(const void* p) {
    uint4 v;
    asm volatile("global_load_dwordx4 %0, %1, off sc0" : "=v"(v) : "v"(p));
    return v;
}
__device__ __forceinline__ uint4 load16_sc01(const void* p) {
    uint4 v;
    asm volatile("global_load_dwordx4 %0, %1, off sc0 sc1" : "=v"(v) : "v"(p));
    return v;
}

// Transpose + split W = [Wx; Wh] into WT_hi/WT_lo [N=2048][K=1024] bf16.
__global__ void prep_w(const float* __restrict__ Wx, const float* __restrict__ Wh,
                       unsigned short* __restrict__ WT_hi, unsigned short* __restrict__ WT_lo) {
    __shared__ float tile[32][33];
    int n0 = (blockIdx.x & 63) * 32;
    int k0 = (blockIdx.x >> 6) * 32;
    int tx = threadIdx.x & 31;
    int ty = threadIdx.x >> 5;
    for (int q = 0; q < 4; ++q) {
        int k = k0 + ty + q * 8;
        int n = n0 + tx;
        float v = (k < Dd) ? Wx[(size_t)k * FOURH + n] : Wh[(size_t)(k - Dd) * FOURH + n];
        tile[ty + q * 8][tx] = v;
    }
    __syncthreads();
    for (int q = 0; q < 4; ++q) {
        int nl = ty + q * 8;
        int kl = tx;
        float v = tile[kl][nl];
        unsigned short hi = f2bf(v);
        unsigned short lo = f2bf(v - bf2f(hi));
        size_t o = (size_t)(n0 + nl) * KTOT + (size_t)(k0 + kl);
        WT_hi[o] = hi;
        WT_lo[o] = lo;
    }
}

// Zero ws[8M..9.5M) (h_pack / fallback c_st+h overlap) and ctrl at 17M.
__global__ void init_state4(char* __restrict__ ws, int persist) {
    long i = (long)blockIdx.x * blockDim.x + threadIdx.x;
    if (i < 98304) {            // 1.5 MB / 16 B
        *(uint4*)(ws + (8u << 20) + i * 16) = (uint4){0, 0, 0, 0};
    }
    if (persist && i < 1024) {
        ((unsigned int*)(ws + (17u << 20)))[i] = 0u;
    }
}

// ---------------- Persistent kernel: W L2-resident + h republish ------------
// 256 WGs x 512 thr (1 WG/CU). Group claimed via HW_REG_XCC_ID (R8-proven
// protocol): group g owns h-cols 64g..64g+63 for ALL rows => W slice 1 MB,
// L2-resident (R10-verified: FETCH 17GB->2.1GB). slot: rt=slot&7 rows,
// cs=slot>>3 cols.
// h path (the R10 wall: 2.1M 8B MALL requests/step):
//   clean group: 32 WGs pull h_pack (512 KB) once via 16B sc0sc1 loads
//   (0.26M req/step total), republish to xcd_buf[g][parity] with plain
//   stores (home L2); consumers read 16B sc0 (L2-served).
//   mixed group: direct 16B sc0sc1 reads of h_pack (placement-independent).
// R9 crash fix applied EVERYWHERE: inline-asm loads are always followed by
// s_waitcnt vmcnt(0) + sched_barrier(0) BEFORE any consumption.
// Sync: intra-group 32-arrival counter + 2-level global tree (8x32 -> 8).
// c in registers; split-3 bf16 MFMA; LDS XOR-swizzle (16B units).
__global__ __launch_bounds__(512) void lstm_persist8(
    const float* __restrict__ X, const int* __restrict__ lengths,
    const unsigned short* __restrict__ WT_hi, const unsigned short* __restrict__ WT_lo,
    const float* __restrict__ bias,
    unsigned int* __restrict__ h_pack,     // [2][Bb*Hh] packed (hi<<16)|lo
    unsigned int* __restrict__ xcd_buf,    // [8][2][Bb*Hh]
    unsigned int* __restrict__ ctrl,
    float* __restrict__ out)
{
    __shared__ unsigned short HLDS[32768];   // 64 KB
    __shared__ unsigned short XLDS[32768];   // 64 KB
    __shared__ float zbuf[8][32][17];        // 17.4 KB
    __shared__ int sgrp, sslt, smix;

    const int tid = threadIdx.x;
    const int w8 = tid >> 6;
    const int lane = tid & 63;
    const int l15 = lane & 15;
    const int q4 = lane >> 4;
    const int klo = q4 * 8;

    unsigned xcc;
    asm volatile("s_getreg_b32 %0, hwreg(HW_REG_XCC_ID, 0, 4)" : "=s"(xcc));
    xcc &= 7u;

    unsigned int* xcdbar = ctrl;             // [g*32] intra-group barrier
    unsigned int* grpcnt = ctrl + 256;       // [g*32] global tree: arrivals
    unsigned int* grprel = ctrl + 512;       // [g*32] global tree: release
    unsigned int* topcnt = ctrl + 768;
    unsigned int* pool   = ctrl + 800;       // [g]
    unsigned int* rcnt   = ctrl + 816;

    // ---- one-time claim + rendezvous + overflow resolution (R8-proven) ----
    if (tid == 0) {
        unsigned my = __hip_atomic_fetch_add(&pool[xcc], 1u, __ATOMIC_RELAXED, __HIP_MEMORY_SCOPE_SYSTEM);
        asm volatile("s_waitcnt vmcnt(0)" ::: "memory");
        __hip_atomic_fetch_add(rcnt, 1u, __ATOMIC_RELAXED, __HIP_MEMORY_SCOPE_SYSTEM);
        while (__hip_atomic_load(rcnt, __ATOMIC_RELAXED, __HIP_MEMORY_SCOPE_SYSTEM) < 256u)
            __builtin_amdgcn_s_sleep(2);
        unsigned cl[8];
        for (int g = 0; g < 8; ++g)
            cl[g] = __hip_atomic_load(&pool[g], __ATOMIC_RELAXED, __HIP_MEMORY_SCOPE_SYSTEM);
        int group = 0, slot = 0;
        if (my < 32u) { group = (int)xcc; slot = (int)my; }
        else {
            int r = (int)my - 32;
            for (int g = 0; g < (int)xcc; ++g) { int e = (int)cl[g] - 32; if (e > 0) r += e; }
            for (int g = 0; g < 8; ++g) {
                int def = 32 - (int)cl[g];
                if (def <= 0) continue;
                if (r < def) { group = g; slot = (int)cl[g] + r; break; }
                r -= def;
            }
        }
        sgrp = group; sslt = slot; smix = (cl[group] < 32u) ? 1 : 0;
    }
    __syncthreads();
    const int group = sgrp;
    const int slot = sslt;
    const int mixed = smix;

    const int rt = slot & 7;
    const int cs = slot >> 3;
    const int r0 = rt * 32;
    const int j0h = group * 64 + cs * 16;
    const int gate = w8 & 3;
    const int khalf = w8 >> 2;

    const size_t HB = (size_t)Bb * Hh;

    // B operand: this lane's gate-column (within L2-resident 1 MB slice)
    const int colg = gate * 512 + j0h + l15;
    const size_t bbase = (size_t)colg * KTOT + (size_t)khalf * 512;
    const unsigned short* bhp = &WT_hi[bbase];
    const unsigned short* blp = &WT_lo[bbase];

    // X staging: thread stages row xr (0..31), k xk0..xk0+31
    const int xr = tid >> 4;
    const int xk0 = (tid & 15) * 32;
    const float* xbase = &X[((size_t)(r0 + xr) * Tt) * Dd + xk0];

    // epilogue ownership: 1 h-element per thread (32 rows x 16 cols)
    const int er = tid >> 4;
    const int ej = tid & 15;
    const int row_g = r0 + er;
    const int col_h = j0h + ej;
    const size_t oidx = (size_t)row_g * Hh + col_h;
    int oT = lengths[row_g] - 1; if (oT < 0) oT = 0;
    const float b0 = bias[col_h], b1 = bias[512 + col_h],
                b2 = bias[1024 + col_h], b3 = bias[1536 + col_h];
    float creg = 0.f;

    unsigned int* mybar = &xcdbar[group * 32];
    unsigned int* mycnt = &grpcnt[group * 32];
    unsigned int* myrel = &grprel[group * 32];

    for (int t = 0; t < Tt; ++t) {
        const int p_r = t & 1;
        const unsigned int* hp_r = h_pack + (size_t)p_r * HB;
        unsigned int* hp_w = h_pack + (size_t)(p_r ^ 1) * HB;
        unsigned int* xb = xcd_buf + ((size_t)(group * 2 + p_r)) * HB;

        // ===== phase A: issue pull of h_pack slice (16 KB/WG, 2x16B/thread) =
        uint4 pv0, pv1;
        const size_t poff = (size_t)slot * 4096 + (size_t)tid * 8;   // uints
        if (!mixed) {
            pv0 = load16_sc01(hp_r + poff);
            pv1 = load16_sc01(hp_r + poff + 4);
        }

        // ===== stage X -> XLDS (plain loads; overlaps pull latency) =========
        {
            const float* xp = xbase + (size_t)t * Dd;
            float4 xv[8];
#pragma unroll
            for (int i = 0; i < 8; ++i) xv[i] = ((const float4*)xp)[i];
            const int ksx = tid & 15;
            const int mi = xr >> 4, lr = xr & 15;
#pragma unroll
            for (int c2 = 0; c2 < 4; ++c2) {
                float vv[8];
                *(float4*)&vv[0] = xv[2 * c2];
                *(float4*)&vv[4] = xv[2 * c2 + 1];
                bf16x8 hv8, lv8;
#pragma unroll
                for (int e = 0; e < 8; ++e) {
                    unsigned short hs = f2bf(vv[e]);
                    hv8[e] = (short)hs;
                    lv8[e] = (short)f2bf(vv[e] - bf2f(hs));
                }
                const int lnw = (c2 * 16 + lr) ^ (ksx & 7);
                *(bf16x8*)&XLDS[(((0 * 2 + mi) * 16 + ksx) * 64 + lnw) * 8] = hv8;
                *(bf16x8*)&XLDS[(((1 * 2 + mi) * 16 + ksx) * 64 + lnw) * 8] = lv8;
            }
        }

        // ===== commit pull -> xcd_buf (R9-fix: wait BEFORE consuming asm) ===
        if (!mixed) {
            asm volatile("s_waitcnt vmcnt(0)" ::: "memory");
            __builtin_amdgcn_sched_barrier(0);
            *(uint4*)(xb + poff) = pv0;
            *(uint4*)(xb + poff + 4) = pv1;
        }
        __syncthreads();   // drains vmcnt (stores in L2) for all threads

        // ===== intra-group barrier: xcd_buf complete before consumption =====
        if (tid == 0) {
            __hip_atomic_fetch_add(mybar, 1u, __ATOMIC_RELAXED, __HIP_MEMORY_SCOPE_SYSTEM);
            const unsigned int tgt = (unsigned int)(t + 1) * 32u;
            while (__hip_atomic_load(mybar, __ATOMIC_RELAXED, __HIP_MEMORY_SCOPE_SYSTEM) < tgt)
                __builtin_amdgcn_s_sleep(2);
        }
        __syncthreads();

        // ===== phase B2: load this WG's 32 h-rows (8x16B/thread) ============
        uint4 hb[8];
        {
            const unsigned int* hsrc = mixed ? hp_r : xb;
            if (!mixed) {
#pragma unroll
                for (int it = 0; it < 4; ++it) {
                    const int c = it * 512 + tid;
                    const int row = c >> 6, k8 = c & 63;
                    const unsigned int* p = hsrc + ((size_t)(r0 + row) * Hh + k8 * 8);
                    hb[it * 2] = load16_sc0(p);
                    hb[it * 2 + 1] = load16_sc0(p + 4);
                }
            } else {
#pragma unroll
                for (int it = 0; it < 4; ++it) {
                    const int c = it * 512 + tid;
                    const int row = c >> 6, k8 = c & 63;
                    const unsigned int* p = hsrc + ((size_t)(r0 + row) * Hh + k8 * 8);
                    hb[it * 2] = load16_sc01(p);
                    hb[it * 2 + 1] = load16_sc01(p + 4);
                }
            }
        }
        asm volatile("s_waitcnt vmcnt(0)" ::: "memory");
        __builtin_amdgcn_sched_barrier(0);

        // ===== unpack h -> HLDS =============================================
#pragma unroll
        for (int it = 0; it < 4; ++it) {
            const int c = it * 512 + tid;
            const int row = c >> 6, k8 = c & 63;
            const int ksh = k8 >> 2, qq = k8 & 3;
            const int mi = row >> 4, lr = row & 15;
            const unsigned int u0 = hb[it * 2].x, u1 = hb[it * 2].y;
            const unsigned int u2 = hb[it * 2].z, u3 = hb[it * 2].w;
            const unsigned int u4 = hb[it * 2 + 1].x, u5 = hb[it * 2 + 1].y;
            const unsigned int u6 = hb[it * 2 + 1].z, u7 = hb[it * 2 + 1].w;
            uint4 hiw, low;
            hiw.x = (u0 >> 16) | (u1 & 0xffff0000u);
            hiw.y = (u2 >> 16) | (u3 & 0xffff0000u);
            hiw.z = (u4 >> 16) | (u5 & 0xffff0000u);
            hiw.w = (u6 >> 16) | (u7 & 0xffff0000u);
            low.x = (u0 & 0xffffu) | (u1 << 16);
            low.y = (u2 & 0xffffu) | (u3 << 16);
            low.z = (u4 & 0xffffu) | (u5 << 16);
            low.w = (u6 & 0xffffu) | (u7 << 16);
            const int lnw = (qq * 16 + lr) ^ (ksh & 7);
            *(uint4*)&HLDS[(((0 * 2 + mi) * 16 + ksh) * 64 + lnw) * 8] = hiw;
            *(uint4*)&HLDS[(((1 * 2 + mi) * 16 + ksh) * 64 + lnw) * 8] = low;
        }
        __syncthreads();

        // ===== compute: split-3 MFMA, A from LDS, B from L2-resident W ======
        const unsigned short* ALDS = khalf ? HLDS : XLDS;
        f32x4 acc[2][3];
#pragma unroll
        for (int mi = 0; mi < 2; ++mi)
#pragma unroll
            for (int s = 0; s < 3; ++s)
                acc[mi][s] = (f32x4){0.f, 0.f, 0.f, 0.f};

#pragma unroll
        for (int ks = 0; ks < 16; ++ks) {
            const int kk = ks * 32 + klo;
            const bf16x8 bh = *(const bf16x8*)&bhp[kk];
            const bf16x8 bl = *(const bf16x8*)&blp[kk];
            const int lnr = lane ^ (ks & 7);
#pragma unroll
            for (int mi = 0; mi < 2; ++mi) {
                const bf16x8 ah = *(const bf16x8*)&ALDS[(((0 * 2 + mi) * 16 + ks) * 64 + lnr) * 8];
                const bf16x8 al = *(const bf16x8*)&ALDS[(((1 * 2 + mi) * 16 + ks) * 64 + lnr) * 8];
                acc[mi][0] = __builtin_amdgcn_mfma_f32_16x16x32_bf16(ah, bh, acc[mi][0], 0, 0, 0);
                acc[mi][1] = __builtin_amdgcn_mfma_f32_16x16x32_bf16(ah, bl, acc[mi][1], 0, 0, 0);
                acc[mi][2] = __builtin_amdgcn_mfma_f32_16x16x32_bf16(al, bh, acc[mi][2], 0, 0, 0);
            }
        }

        // z tiles -> LDS (C/D: col=lane&15, row=(lane>>4)*4+r)
#pragma unroll
        for (int mi = 0; mi < 2; ++mi) {
            const f32x4 z = acc[mi][0] + acc[mi][1] + acc[mi][2];
#pragma unroll
            for (int r = 0; r < 4; ++r)
                zbuf[w8][mi * 16 + q4 * 4 + r][l15] = z[r];
        }
        __syncthreads();

        // ===== epilogue ======================================================
        float zi = zbuf[0][er][ej] + zbuf[4][er][ej] + b0;
        float zf = zbuf[1][er][ej] + zbuf[5][er][ej] + b1;
        float zg = zbuf[2][er][ej] + zbuf[6][er][ej] + b2;
        float zo = zbuf[3][er][ej] + zbuf[7][er][ej] + b3;
        float ig = 1.f / (1.f + expf(-zi));
        float fg = 1.f / (1.f + expf(-zf));
        float gg = tanhf(zg);
        float og = 1.f / (1.f + expf(-zo));
        float cn = fg * creg + ig * gg;
        creg = cn;
        float hn = og * tanhf(cn);
        unsigned short hh = f2bf(hn);
        unsigned short hl = f2bf(hn - bf2f(hh));
        unsigned int up = ((unsigned int)hh << 16) | (unsigned int)hl;
        __hip_atomic_store(&hp_w[oidx], up, __ATOMIC_RELAXED, __HIP_MEMORY_SCOPE_SYSTEM);
        if (t == oT) out[oidx] = hn;

        // ===== global barrier: 2-level tree (8x32 parallel -> 8 leaders) ====
        if (t < Tt - 1) {
            asm volatile("s_waitcnt vmcnt(0)" ::: "memory");  // h stores at MALL
            __syncthreads();
            if (tid == 0) {
                __hip_atomic_fetch_add(mycnt, 1u, __ATOMIC_RELAXED, __HIP_MEMORY_SCOPE_SYSTEM);
                const unsigned int tg = (unsigned int)(t + 1);
                if (slot == 0) {
                    while (__hip_atomic_load(mycnt, __ATOMIC_RELAXED, __HIP_MEMORY_SCOPE_SYSTEM) < tg * 32u)
                        __builtin_amdgcn_s_sleep(2);
                    __hip_atomic_fetch_add(topcnt, 1u, __ATOMIC_RELAXED, __HIP_MEMORY_SCOPE_SYSTEM);
                    while (__hip_atomic_load(topcnt, __ATOMIC_RELAXED, __HIP_MEMORY_SCOPE_SYSTEM) < tg * 8u)
                        __builtin_amdgcn_s_sleep(2);
                    __hip_atomic_store(myrel, tg, __ATOMIC_RELAXED, __HIP_MEMORY_SCOPE_SYSTEM);
                } else {
                    while (__hip_atomic_load(myrel, __ATOMIC_RELAXED, __HIP_MEMORY_SCOPE_SYSTEM) < tg)
                        __builtin_amdgcn_s_sleep(2);
                }
            }
            __syncthreads();
        }
    }
}

// ---------------- Fallback: per-step kernel (round-4 proven path) ----------
__global__ __launch_bounds__(512) void lstm_step4(
    const float* __restrict__ X, const int* __restrict__ lengths,
    const unsigned short* __restrict__ WT_hi, const unsigned short* __restrict__ WT_lo,
    const float* __restrict__ bias,
    float* __restrict__ c_st,
    const unsigned short* __restrict__ h_r_hi, const unsigned short* __restrict__ h_r_lo,
    unsigned short* __restrict__ h_w_hi, unsigned short* __restrict__ h_w_lo,
    float* __restrict__ out, int t)
{
    __shared__ float zbuf[8][16][17];

    const int bx = blockIdx.x;
    const int xcd = bx & 7;
    const int rem = bx >> 3;
    const int m0 = (rem & 15) * 16;
    const int col_group = xcd * 4 + (rem >> 4);
    const int hc0 = col_group * 16;
    const int tid = threadIdx.x;
    const int w8 = tid >> 6;
    const int lane = tid & 63;
    const int gate = w8 & 3;
    const int khalf = w8 >> 2;

    f32x4 ahh = (f32x4){0,0,0,0}, ahl = (f32x4){0,0,0,0}, alh = (f32x4){0,0,0,0};

    const int colk = gate * 512 + hc0 + (lane & 15);
    const size_t bbase = (size_t)colk * KTOT;
    const int klo = (lane >> 4) * 8;
    const int row = m0 + (lane & 15);

    if (khalf == 0) {
        const float* xrow = &X[((size_t)row * Tt + t) * Dd];
        const unsigned short* bhp = &WT_hi[bbase];
        const unsigned short* blp = &WT_lo[bbase];
#pragma unroll
        for (int ks = 0; ks < 16; ++ks) {
            const int kk = ks * 32 + klo;
            const float4 v0 = *(const float4*)&xrow[kk];
            const float4 v1 = *(const float4*)&xrow[kk + 4];
            float vv[8] = {v0.x, v0.y, v0.z, v0.w, v1.x, v1.y, v1.z, v1.w};
            bf16x8 ah, al;
#pragma unroll
            for (int e = 0; e < 8; ++e) {
                unsigned short hi = f2bf(vv[e]);
                ah[e] = (short)hi;
                al[e] = (short)f2bf(vv[e] - bf2f(hi));
            }
            const bf16x8 bh = *(const bf16x8*)&bhp[kk];
            const bf16x8 bl = *(const bf16x8*)&blp[kk];
            ahh = __builtin_amdgcn_mfma_f32_16x16x32_bf16(ah, bh, ahh, 0, 0, 0);
            ahl = __builtin_amdgcn_mfma_f32_16x16x32_bf16(ah, bl, ahl, 0, 0, 0);
            alh = __builtin_amdgcn_mfma_f32_16x16x32_bf16(al, bh, alh, 0, 0, 0);
        }
    } else {
        const unsigned short* hrh = &h_r_hi[(size_t)row * Hh];
        const unsigned short* hrl = &h_r_lo[(size_t)row * Hh];
        const unsigned short* bhp = &WT_hi[bbase + 512];
        const unsigned short* blp = &WT_lo[bbase + 512];
#pragma unroll
        for (int ks = 0; ks < 16; ++ks) {
            const int kk = ks * 32 + klo;
            const bf16x8 ah = *(const bf16x8*)&hrh[kk];
            const bf16x8 al = *(const bf16x8*)&hrl[kk];
            const bf16x8 bh = *(const bf16x8*)&bhp[kk];
            const bf16x8 bl = *(const bf16x8*)&blp[kk];
            ahh = __builtin_amdgcn_mfma_f32_16x16x32_bf16(ah, bh, ahh, 0, 0, 0);
            ahl = __builtin_amdgcn_mfma_f32_16x16x32_bf16(ah, bl, ahl, 0, 0, 0);
            alh = __builtin_amdgcn_mfma_f32_16x16x32_bf16(al, bh, alh, 0, 0, 0);
        }
    }

    const f32x4 z = ahh + ahl + alh;
#pragma unroll
    for (int r = 0; r < 4; ++r)
        zbuf[w8][(lane >> 4) * 4 + r][lane & 15] = z[r];
    __syncthreads();

    if (tid < 256) {
        const int r = tid >> 4;
        const int j = tid & 15;
        const int row_g = m0 + r;
        const int col_g = hc0 + j;
        float zi = zbuf[0][r][j] + zbuf[4][r][j] + bias[col_g];
        float zf = zbuf[1][r][j] + zbuf[5][r][j] + bias[512 + col_g];
        float zg = zbuf[2][r][j] + zbuf[6][r][j] + bias[1024 + col_g];
        float zo = zbuf[3][r][j] + zbuf[7][r][j] + bias[1536 + col_g];
        float ig = 1.f / (1.f + expf(-zi));
        float fg = 1.f / (1.f + expf(-zf));
        float gg = tanhf(zg);
        float og = 1.f / (1.f + expf(-zo));
        const size_t idx = (size_t)row_g * Hh + col_g;
        float cn = fg * c_st[idx] + ig * gg;
        float hn = og * tanhf(cn);
        c_st[idx] = cn;
        unsigned short hh = f2bf(hn);
        h_w_hi[idx] = hh;
        h_w_lo[idx] = f2bf(hn - bf2f(hh));
        int len = lengths[row_g];
        int oidx = len - 1; if (oidx < 0) oidx = 0;
        if (t == oidx) out[idx] = hn;
    }
}

extern "C" void kernel_launch(void* const* d_in, const int* in_sizes, int n_in,
                              void* d_out, int out_size, void* d_ws, size_t ws_size,
                              hipStream_t stream) {
    const float* X = (const float*)d_in[0];
    const int* lengths = (const int*)d_in[1];
    const float* Wx = (const float*)d_in[2];
    const float* Wh = (const float*)d_in[3];
    const float* bias = (const float*)d_in[4];
    float* out = (float*)d_out;

    char* ws = (char*)d_ws;
    unsigned short* WT_hi = (unsigned short*)ws;                               // 0..4M
    unsigned short* WT_lo = (unsigned short*)(ws + (4u << 20));                // 4..8M
    // persistent-path buffers
    unsigned int* h_pack = (unsigned int*)(ws + (8u << 20));                   // 8..9M
    unsigned int* xcd_buf = (unsigned int*)(ws + (9u << 20));                  // 9..17M
    unsigned int* ctrl = (unsigned int*)(ws + (17u << 20));                    // 17M..+4K
    // fallback-path buffers (overlap h_pack region; paths are exclusive)
    float* c_st = (float*)(ws + (8u << 20));
    unsigned short* h_base = (unsigned short*)(ws + (8u << 20) + (512u << 10));
    const size_t HB = (size_t)Bb * Hh;
    unsigned short* h_hi0 = h_base;
    unsigned short* h_lo0 = h_base + HB;
    unsigned short* h_hi1 = h_base + 2 * HB;
    unsigned short* h_lo1 = h_base + 3 * HB;

    const size_t NEED_PERSIST = (17u << 20) + 4096u;
    const int can_persist = (ws_size >= NEED_PERSIST) ? 1 : 0;

    hipLaunchKernelGGL(prep_w, dim3(2048), dim3(256), 0, stream, Wx, Wh, WT_hi, WT_lo);
    hipLaunchKernelGGL(init_state4, dim3(512), dim3(256), 0, stream, ws, can_persist);

    hipError_t err = hipErrorUnknown;
    if (can_persist) {
        void* args[] = { (void*)&X, (void*)&lengths, (void*)&WT_hi, (void*)&WT_lo,
                         (void*)&bias, (void*)&h_pack, (void*)&xcd_buf, (void*)&ctrl,
                         (void*)&out };
        err = hipLaunchCooperativeKernel((const void*)lstm_persist8,
                                         dim3(256), dim3(512), args, 0, stream);
    }
    if (err != hipSuccess) {
        for (int t = 0; t < Tt; ++t) {
            const bool even = (t & 1) == 0;
            hipLaunchKernelGGL(lstm_step4, dim3(512), dim3(512), 0, stream,
                               X, lengths, WT_hi, WT_lo, bias, c_st,
                               even ? h_hi0 : h_hi1, even ? h_lo0 : h_lo1,
                               even ? h_hi1 : h_hi0, even ? h_lo1 : h_lo0,
                               out, t);
        }
    }
}

// Round 12
// 7106.587 us; speedup vs baseline: 1.2765x; 1.2765x over previous
//
#include <hip/hip_runtime.h>

#define Bb 256
#define Tt 512
#define Dd 512
#define Hh 512
#define KTOT 1024
#define FOURH 2048

typedef __attribute__((ext_vector_type(8))) short bf16x8;
typedef __attribute__((ext_vector_type(4))) float f32x4;

__device__ __forceinline__ unsigned short f2bf(float f) {
    union { float f; unsigned u; } x; x.f = f;
    unsigned u = x.u;
    unsigned r = u + 0x7FFFu + ((u >> 16) & 1u);
    return (unsigned short)(r >> 16);
}
__device__ __forceinline__ float bf2f(unsigned short s) {
    union { unsigned u; float f; } x; x.u = ((unsigned)s) << 16;
    return x.f;
}

__device__ __forceinline__ uint4 load16_sc01(const void* p) {
    uint4 v;
    asm volatile("global_load_dwordx4 %0, %1, off sc0 sc1" : "=v"(v) : "v"(p));
    return v;
}

// Transpose + split W = [Wx; Wh] into WT_hi/WT_lo [N=2048][K=1024] bf16.
__global__ void prep_w(const float* __restrict__ Wx, const float* __restrict__ Wh,
                       unsigned short* __restrict__ WT_hi, unsigned short* __restrict__ WT_lo) {
    __shared__ float tile[32][33];
    int n0 = (blockIdx.x & 63) * 32;
    int k0 = (blockIdx.x >> 6) * 32;
    int tx = threadIdx.x & 31;
    int ty = threadIdx.x >> 5;
    for (int q = 0; q < 4; ++q) {
        int k = k0 + ty + q * 8;
        int n = n0 + tx;
        float v = (k < Dd) ? Wx[(size_t)k * FOURH + n] : Wh[(size_t)(k - Dd) * FOURH + n];
        tile[ty + q * 8][tx] = v;
    }
    __syncthreads();
    for (int q = 0; q < 4; ++q) {
        int nl = ty + q * 8;
        int kl = tx;
        float v = tile[kl][nl];
        unsigned short hi = f2bf(v);
        unsigned short lo = f2bf(v - bf2f(hi));
        size_t o = (size_t)(n0 + nl) * KTOT + (size_t)(k0 + kl);
        WT_hi[o] = hi;
        WT_lo[o] = lo;
    }
}

// Zero ws[8M..9.5M) (h_pack / fallback c_st+h overlap) and ctrl at 9.5M.
__global__ void init_state3(char* __restrict__ ws, int persist) {
    long i = (long)blockIdx.x * blockDim.x + threadIdx.x;
    if (i < 98304) {            // 1.5 MB / 16 B
        *(uint4*)(ws + (8u << 20) + i * 16) = (uint4){0, 0, 0, 0};
    }
    if (persist && i < 512) {
        ((unsigned int*)(ws + (8u << 20) + (1536u << 10)))[i] = 0u;
    }
}

// ---------------- Persistent kernel: column partition, cohort barriers ------
// 256 WGs x 512 thr (1 WG/CU). group = bx&7 (XCD under round-robin — perf
// heuristic only). Group owns h-cols 64g..64g+63 for ALL rows => W slice
// 1 MB/XCD, L2-resident (R10-verified). slot = bx>>3: rt = slot&7 -> rows
// 32rt..+31; cs = slot>>3 -> 16 h-cols.
// KEY (R12): the 32 WGs sharing rt form a CLOSED system (they produce and
// consume exactly h rows 32rt..+31). Sync = 8 independent per-rt 32-arrival
// relaxed counters (padded lines) — no global barrier.
// h exchange: packed (hi<<16|lo) in h_pack[parity]; producers store via
// system-scope relaxed atomics; consumers read 16B sc0sc1 asm loads with
// R9-fix discipline (waitcnt+sched_barrier BEFORE consumption; R11-proven).
// c in registers; split-3 bf16 MFMA; LDS XOR-swizzle (16B units).
__global__ __launch_bounds__(512) void lstm_persist9(
    const float* __restrict__ X, const int* __restrict__ lengths,
    const unsigned short* __restrict__ WT_hi, const unsigned short* __restrict__ WT_lo,
    const float* __restrict__ bias,
    unsigned int* __restrict__ h_pack,     // [2][Bb*Hh] packed (hi<<16)|lo
    unsigned int* __restrict__ ctrl,
    float* __restrict__ out)
{
    __shared__ unsigned short HLDS[32768];   // 64 KB
    __shared__ unsigned short XLDS[32768];   // 64 KB
    __shared__ float zbuf[8][32][17];        // 17.4 KB

    const int bx = blockIdx.x;
    const int group = bx & 7;
    const int slot = bx >> 3;
    const int rt = slot & 7;
    const int cs = slot >> 3;
    const int r0 = rt * 32;
    const int j0h = group * 64 + cs * 16;
    const int tid = threadIdx.x;
    const int w8 = tid >> 6;
    const int lane = tid & 63;
    const int l15 = lane & 15;
    const int q4 = lane >> 4;
    const int klo = q4 * 8;
    const int gate = w8 & 3;
    const int khalf = w8 >> 2;

    const size_t HB = (size_t)Bb * Hh;

    // B operand: this lane's gate-column (within L2-resident 1 MB slice)
    const int colg = gate * 512 + j0h + l15;
    const size_t bbase = (size_t)colg * KTOT + (size_t)khalf * 512;
    const unsigned short* bhp = &WT_hi[bbase];
    const unsigned short* blp = &WT_lo[bbase];

    // X staging: thread stages row xr (0..31), k xk0..xk0+31
    const int xr = tid >> 4;
    const int xk0 = (tid & 15) * 32;
    const float* xbase = &X[((size_t)(r0 + xr) * Tt) * Dd + xk0];

    // epilogue ownership: 1 h-element per thread (32 rows x 16 cols)
    const int er = tid >> 4;
    const int ej = tid & 15;
    const int row_g = r0 + er;
    const int col_h = j0h + ej;
    const size_t oidx = (size_t)row_g * Hh + col_h;
    int oT = lengths[row_g] - 1; if (oT < 0) oT = 0;
    const float b0 = bias[col_h], b1 = bias[512 + col_h],
                b2 = bias[1024 + col_h], b3 = bias[1536 + col_h];
    float creg = 0.f;

    unsigned int* myflag = &ctrl[rt * 32];   // per-rt cohort counter, 128B apart

    for (int t = 0; t < Tt; ++t) {
        const int p_r = t & 1;
        const unsigned int* hp_r = h_pack + (size_t)p_r * HB;
        unsigned int* hp_w = h_pack + (size_t)(p_r ^ 1) * HB;

        // ===== issue h loads (16B sc0sc1; MALL latency hides under X stage) =
        uint4 hb[8];
#pragma unroll
        for (int it = 0; it < 4; ++it) {
            const int c = it * 512 + tid;       // 0..2047: row(32) x k8(64)
            const int row = c >> 6, k8 = c & 63;
            const unsigned int* p = hp_r + ((size_t)(r0 + row) * Hh + k8 * 8);
            hb[it * 2] = load16_sc01(p);
            hb[it * 2 + 1] = load16_sc01(p + 4);
        }

        // ===== stage X -> XLDS (plain loads; overlaps h latency) ============
        {
            const float* xp = xbase + (size_t)t * Dd;
            float4 xv[8];
#pragma unroll
            for (int i = 0; i < 8; ++i) xv[i] = ((const float4*)xp)[i];
            const int ksx = tid & 15;
            const int mi = xr >> 4, lr = xr & 15;
#pragma unroll
            for (int c2 = 0; c2 < 4; ++c2) {
                float vv[8];
                *(float4*)&vv[0] = xv[2 * c2];
                *(float4*)&vv[4] = xv[2 * c2 + 1];
                bf16x8 hv8, lv8;
#pragma unroll
                for (int e = 0; e < 8; ++e) {
                    unsigned short hs = f2bf(vv[e]);
                    hv8[e] = (short)hs;
                    lv8[e] = (short)f2bf(vv[e] - bf2f(hs));
                }
                const int lnw = (c2 * 16 + lr) ^ (ksx & 7);
                *(bf16x8*)&XLDS[(((0 * 2 + mi) * 16 + ksx) * 64 + lnw) * 8] = hv8;
                *(bf16x8*)&XLDS[(((1 * 2 + mi) * 16 + ksx) * 64 + lnw) * 8] = lv8;
            }
        }

        // ===== R9-fix: drain ALL loads before touching asm results ==========
        asm volatile("s_waitcnt vmcnt(0)" ::: "memory");
        __builtin_amdgcn_sched_barrier(0);

        // ===== unpack h -> HLDS =============================================
#pragma unroll
        for (int it = 0; it < 4; ++it) {
            const int c = it * 512 + tid;
            const int row = c >> 6, k8 = c & 63;
            const int ksh = k8 >> 2, qq = k8 & 3;
            const int mi = row >> 4, lr = row & 15;
            const unsigned int u0 = hb[it * 2].x, u1 = hb[it * 2].y;
            const unsigned int u2 = hb[it * 2].z, u3 = hb[it * 2].w;
            const unsigned int u4 = hb[it * 2 + 1].x, u5 = hb[it * 2 + 1].y;
            const unsigned int u6 = hb[it * 2 + 1].z, u7 = hb[it * 2 + 1].w;
            uint4 hiw, low;
            hiw.x = (u0 >> 16) | (u1 & 0xffff0000u);
            hiw.y = (u2 >> 16) | (u3 & 0xffff0000u);
            hiw.z = (u4 >> 16) | (u5 & 0xffff0000u);
            hiw.w = (u6 >> 16) | (u7 & 0xffff0000u);
            low.x = (u0 & 0xffffu) | (u1 << 16);
            low.y = (u2 & 0xffffu) | (u3 << 16);
            low.z = (u4 & 0xffffu) | (u5 << 16);
            low.w = (u6 & 0xffffu) | (u7 << 16);
            const int lnw = (qq * 16 + lr) ^ (ksh & 7);
            *(uint4*)&HLDS[(((0 * 2 + mi) * 16 + ksh) * 64 + lnw) * 8] = hiw;
            *(uint4*)&HLDS[(((1 * 2 + mi) * 16 + ksh) * 64 + lnw) * 8] = low;
        }
        __syncthreads();

        // ===== compute: split-3 MFMA, A from LDS, B from L2-resident W ======
        const unsigned short* ALDS = khalf ? HLDS : XLDS;
        f32x4 acc[2][3];
#pragma unroll
        for (int mi = 0; mi < 2; ++mi)
#pragma unroll
            for (int s = 0; s < 3; ++s)
                acc[mi][s] = (f32x4){0.f, 0.f, 0.f, 0.f};

#pragma unroll
        for (int ks = 0; ks < 16; ++ks) {
            const int kk = ks * 32 + klo;
            const bf16x8 bh = *(const bf16x8*)&bhp[kk];
            const bf16x8 bl = *(const bf16x8*)&blp[kk];
            const int lnr = lane ^ (ks & 7);
#pragma unroll
            for (int mi = 0; mi < 2; ++mi) {
                const bf16x8 ah = *(const bf16x8*)&ALDS[(((0 * 2 + mi) * 16 + ks) * 64 + lnr) * 8];
                const bf16x8 al = *(const bf16x8*)&ALDS[(((1 * 2 + mi) * 16 + ks) * 64 + lnr) * 8];
                acc[mi][0] = __builtin_amdgcn_mfma_f32_16x16x32_bf16(ah, bh, acc[mi][0], 0, 0, 0);
                acc[mi][1] = __builtin_amdgcn_mfma_f32_16x16x32_bf16(ah, bl, acc[mi][1], 0, 0, 0);
                acc[mi][2] = __builtin_amdgcn_mfma_f32_16x16x32_bf16(al, bh, acc[mi][2], 0, 0, 0);
            }
        }

        // z tiles -> LDS (C/D: col=lane&15, row=(lane>>4)*4+r)
#pragma unroll
        for (int mi = 0; mi < 2; ++mi) {
            const f32x4 z = acc[mi][0] + acc[mi][1] + acc[mi][2];
#pragma unroll
            for (int r = 0; r < 4; ++r)
                zbuf[w8][mi * 16 + q4 * 4 + r][l15] = z[r];
        }
        __syncthreads();

        // ===== epilogue ======================================================
        float zi = zbuf[0][er][ej] + zbuf[4][er][ej] + b0;
        float zf = zbuf[1][er][ej] + zbuf[5][er][ej] + b1;
        float zg = zbuf[2][er][ej] + zbuf[6][er][ej] + b2;
        float zo = zbuf[3][er][ej] + zbuf[7][er][ej] + b3;
        float ig = 1.f / (1.f + expf(-zi));
        float fg = 1.f / (1.f + expf(-zf));
        float gg = tanhf(zg);
        float og = 1.f / (1.f + expf(-zo));
        float cn = fg * creg + ig * gg;
        creg = cn;
        float hn = og * tanhf(cn);
        unsigned short hh = f2bf(hn);
        unsigned short hl = f2bf(hn - bf2f(hh));
        unsigned int up = ((unsigned int)hh << 16) | (unsigned int)hl;
        __hip_atomic_store(&hp_w[oidx], up, __ATOMIC_RELAXED, __HIP_MEMORY_SCOPE_SYSTEM);
        if (t == oT) out[oidx] = hn;

        // ===== per-rt cohort barrier: 32 arrivals on a private line =========
        if (t < Tt - 1) {
            asm volatile("s_waitcnt vmcnt(0)" ::: "memory");  // h stores at MALL
            __syncthreads();
            if (tid == 0) {
                __hip_atomic_fetch_add(myflag, 1u, __ATOMIC_RELAXED, __HIP_MEMORY_SCOPE_SYSTEM);
                const unsigned int tgt = (unsigned int)(t + 1) * 32u;
                while (__hip_atomic_load(myflag, __ATOMIC_RELAXED, __HIP_MEMORY_SCOPE_SYSTEM) < tgt)
                    __builtin_amdgcn_s_sleep(2);
            }
            __syncthreads();
        }
    }
}

// ---------------- Fallback: per-step kernel (round-4 proven path) ----------
__global__ __launch_bounds__(512) void lstm_step4(
    const float* __restrict__ X, const int* __restrict__ lengths,
    const unsigned short* __restrict__ WT_hi, const unsigned short* __restrict__ WT_lo,
    const float* __restrict__ bias,
    float* __restrict__ c_st,
    const unsigned short* __restrict__ h_r_hi, const unsigned short* __restrict__ h_r_lo,
    unsigned short* __restrict__ h_w_hi, unsigned short* __restrict__ h_w_lo,
    float* __restrict__ out, int t)
{
    __shared__ float zbuf[8][16][17];

    const int bx = blockIdx.x;
    const int xcd = bx & 7;
    const int rem = bx >> 3;
    const int m0 = (rem & 15) * 16;
    const int col_group = xcd * 4 + (rem >> 4);
    const int hc0 = col_group * 16;
    const int tid = threadIdx.x;
    const int w8 = tid >> 6;
    const int lane = tid & 63;
    const int gate = w8 & 3;
    const int khalf = w8 >> 2;

    f32x4 ahh = (f32x4){0,0,0,0}, ahl = (f32x4){0,0,0,0}, alh = (f32x4){0,0,0,0};

    const int colk = gate * 512 + hc0 + (lane & 15);
    const size_t bbase = (size_t)colk * KTOT;
    const int klo = (lane >> 4) * 8;
    const int row = m0 + (lane & 15);

    if (khalf == 0) {
        const float* xrow = &X[((size_t)row * Tt + t) * Dd];
        const unsigned short* bhp = &WT_hi[bbase];
        const unsigned short* blp = &WT_lo[bbase];
#pragma unroll
        for (int ks = 0; ks < 16; ++ks) {
            const int kk = ks * 32 + klo;
            const float4 v0 = *(const float4*)&xrow[kk];
            const float4 v1 = *(const float4*)&xrow[kk + 4];
            float vv[8] = {v0.x, v0.y, v0.z, v0.w, v1.x, v1.y, v1.z, v1.w};
            bf16x8 ah, al;
#pragma unroll
            for (int e = 0; e < 8; ++e) {
                unsigned short hi = f2bf(vv[e]);
                ah[e] = (short)hi;
                al[e] = (short)f2bf(vv[e] - bf2f(hi));
            }
            const bf16x8 bh = *(const bf16x8*)&bhp[kk];
            const bf16x8 bl = *(const bf16x8*)&blp[kk];
            ahh = __builtin_amdgcn_mfma_f32_16x16x32_bf16(ah, bh, ahh, 0, 0, 0);
            ahl = __builtin_amdgcn_mfma_f32_16x16x32_bf16(ah, bl, ahl, 0, 0, 0);
            alh = __builtin_amdgcn_mfma_f32_16x16x32_bf16(al, bh, alh, 0, 0, 0);
        }
    } else {
        const unsigned short* hrh = &h_r_hi[(size_t)row * Hh];
        const unsigned short* hrl = &h_r_lo[(size_t)row * Hh];
        const unsigned short* bhp = &WT_hi[bbase + 512];
        const unsigned short* blp = &WT_lo[bbase + 512];
#pragma unroll
        for (int ks = 0; ks < 16; ++ks) {
            const int kk = ks * 32 + klo;
            const bf16x8 ah = *(const bf16x8*)&hrh[kk];
            const bf16x8 al = *(const bf16x8*)&hrl[kk];
            const bf16x8 bh = *(const bf16x8*)&bhp[kk];
            const bf16x8 bl = *(const bf16x8*)&blp[kk];
            ahh = __builtin_amdgcn_mfma_f32_16x16x32_bf16(ah, bh, ahh, 0, 0, 0);
            ahl = __builtin_amdgcn_mfma_f32_16x16x32_bf16(ah, bl, ahl, 0, 0, 0);
            alh = __builtin_amdgcn_mfma_f32_16x16x32_bf16(al, bh, alh, 0, 0, 0);
        }
    }

    const f32x4 z = ahh + ahl + alh;
#pragma unroll
    for (int r = 0; r < 4; ++r)
        zbuf[w8][(lane >> 4) * 4 + r][lane & 15] = z[r];
    __syncthreads();

    if (tid < 256) {
        const int r = tid >> 4;
        const int j = tid & 15;
        const int row_g = m0 + r;
        const int col_g = hc0 + j;
        float zi = zbuf[0][r][j] + zbuf[4][r][j] + bias[col_g];
        float zf = zbuf[1][r][j] + zbuf[5][r][j] + bias[512 + col_g];
        float zg = zbuf[2][r][j] + zbuf[6][r][j] + bias[1024 + col_g];
        float zo = zbuf[3][r][j] + zbuf[7][r][j] + bias[1536 + col_g];
        float ig = 1.f / (1.f + expf(-zi));
        float fg = 1.f / (1.f + expf(-zf));
        float gg = tanhf(zg);
        float og = 1.f / (1.f + expf(-zo));
        const size_t idx = (size_t)row_g * Hh + col_g;
        float cn = fg * c_st[idx] + ig * gg;
        float hn = og * tanhf(cn);
        c_st[idx] = cn;
        unsigned short hh = f2bf(hn);
        h_w_hi[idx] = hh;
        h_w_lo[idx] = f2bf(hn - bf2f(hh));
        int len = lengths[row_g];
        int oidx = len - 1; if (oidx < 0) oidx = 0;
        if (t == oidx) out[idx] = hn;
    }
}

extern "C" void kernel_launch(void* const* d_in, const int* in_sizes, int n_in,
                              void* d_out, int out_size, void* d_ws, size_t ws_size,
                              hipStream_t stream) {
    const float* X = (const float*)d_in[0];
    const int* lengths = (const int*)d_in[1];
    const float* Wx = (const float*)d_in[2];
    const float* Wh = (const float*)d_in[3];
    const float* bias = (const float*)d_in[4];
    float* out = (float*)d_out;

    char* ws = (char*)d_ws;
    unsigned short* WT_hi = (unsigned short*)ws;                               // 0..4M
    unsigned short* WT_lo = (unsigned short*)(ws + (4u << 20));                // 4..8M
    // persistent-path buffers
    unsigned int* h_pack = (unsigned int*)(ws + (8u << 20));                   // 8..9M
    unsigned int* ctrl = (unsigned int*)(ws + (8u << 20) + (1536u << 10));     // 9.5M..+2K
    // fallback-path buffers (overlap h_pack region; paths are exclusive)
    float* c_st = (float*)(ws + (8u << 20));
    unsigned short* h_base = (unsigned short*)(ws + (8u << 20) + (512u << 10));
    const size_t HB = (size_t)Bb * Hh;
    unsigned short* h_hi0 = h_base;
    unsigned short* h_lo0 = h_base + HB;
    unsigned short* h_hi1 = h_base + 2 * HB;
    unsigned short* h_lo1 = h_base + 3 * HB;

    const size_t NEED_PERSIST = (8u << 20) + (1536u << 10) + 4096u;
    const int can_persist = (ws_size >= NEED_PERSIST) ? 1 : 0;

    hipLaunchKernelGGL(prep_w, dim3(2048), dim3(256), 0, stream, Wx, Wh, WT_hi, WT_lo);
    hipLaunchKernelGGL(init_state3, dim3(512), dim3(256), 0, stream, ws, can_persist);

    hipError_t err = hipErrorUnknown;
    if (can_persist) {
        void* args[] = { (void*)&X, (void*)&lengths, (void*)&WT_hi, (void*)&WT_lo,
                         (void*)&bias, (void*)&h_pack, (void*)&ctrl, (void*)&out };
        err = hipLaunchCooperativeKernel((const void*)lstm_persist9,
                                         dim3(256), dim3(512), args, 0, stream);
    }
    if (err != hipSuccess) {
        for (int t = 0; t < Tt; ++t) {
            const bool even = (t & 1) == 0;
            hipLaunchKernelGGL(lstm_step4, dim3(512), dim3(512), 0, stream,
                               X, lengths, WT_hi, WT_lo, bias, c_st,
                               even ? h_hi0 : h_hi1, even ? h_lo0 : h_lo1,
                               even ? h_hi1 : h_hi0, even ? h_lo1 : h_lo0,
                               out, t);
        }
    }
}